// Round 13
// baseline (243.743 us; speedup 1.0000x reference)
//
#include <hip/hip_runtime.h>
#include <math.h>

typedef unsigned long long u64;
typedef __attribute__((ext_vector_type(8))) short bfrag;   // 8 bf16 (guide §3 verified typedef)
typedef __attribute__((ext_vector_type(4))) float ffrag;   // 4 fp32 accumulator

// ---------------------------------------------------------------------------
// split fp32 -> (hi,lo) bf16 pair packed in one dword (hi in low 16 bits).
// hi = truncation; residual is exact (Sterbenz); lo = RNE(residual).
// hi+lo represents x to ~2^-17 relative -> split-bf16 GEMM ~ fp32 accurate.
// ---------------------------------------------------------------------------
__device__ __forceinline__ unsigned splitpack(float x)
{
    unsigned u = __float_as_uint(x);
    unsigned hi = u >> 16;
    float r = x - __uint_as_float(hi << 16);
    unsigned v = __float_as_uint(r);
    unsigned lo = (v + 0x7FFFu + ((v >> 16) & 1u)) >> 16;
    return hi | (lo << 16);
}

// ---------------------------------------------------------------------------
// Convert W (K x 256 row-major fp32) to MFMA-fragment-ordered split-bf16,
// hi-plane and lo-plane stored SEPARATELY (ushort each) so the GEMM hot loop
// loads fragments as single 16B reads with zero unpack VALU ops.
// ushort index f = ((ct*KB + kb)*64 + lane)*8 + i holds
//   W[kb*32 + (lane>>4)*8 + i][ct*16 + (lane&15)]   (KB = K/32)
// SAME (lane,elem)->k mapping as the A fragments -> any HW k-permutation
// cancels in the summed dot product (verified by r12 passing).
// ---------------------------------------------------------------------------
__device__ void conv_wfrag(const float* __restrict__ W,
                           unsigned short* __restrict__ wh,
                           unsigned short* __restrict__ wl,
                           int KB, int gid, int stride)
{
    int total = KB * 32 * 256;
    for (int f = gid; f < total; f += stride) {
        int i = f & 7;
        int l = (f >> 3) & 63;
        int t = f >> 9;
        int kb = t % KB, ct = t / KB;
        int k = kb * 32 + (l >> 4) * 8 + i;
        int n = ct * 16 + (l & 15);
        unsigned pk = splitpack(W[k * 256 + n]);
        wh[f] = (unsigned short)pk;
        wl[f] = (unsigned short)(pk >> 16);
    }
}

// ---------------------------------------------------------------------------
// Kernel 1: KNN (bit-exact vs np/fp32 reference) + fused 3-scale surface conv.
// One wave per row, 4 rows per 256-thread block. LDS ~22.7 KB. (round-0 body)
// Tail: converts the 4 W matrices to two-plane fragment-ordered split-bf16.
// ---------------------------------------------------------------------------
__global__ __launch_bounds__(256) void knnsurf_kernel(
    const float* __restrict__ verts,
    int* __restrict__ idx_out, float4* __restrict__ nd_out,
    const float* __restrict__ dl, const float* __restrict__ dm,
    const float* __restrict__ dg,
    float* __restrict__ raw_l, float* __restrict__ raw_m, float* __restrict__ raw_g,
    const float* __restrict__ Wm1, const float* __restrict__ Wg1,
    const float* __restrict__ Wg2, const float* __restrict__ Wdn,
    unsigned short* __restrict__ wh_m1, unsigned short* __restrict__ wl_m1,
    unsigned short* __restrict__ wh_g1, unsigned short* __restrict__ wl_g1,
    unsigned short* __restrict__ wh_g2, unsigned short* __restrict__ wl_g2,
    unsigned short* __restrict__ wh_dn, unsigned short* __restrict__ wl_dn)
{
    __shared__ float4 vps[1024];                    // x,y,z,sq  (16 KB)
    __shared__ __align__(16) u64 cand[4][208];      // 6.7 KB; row = 16B-aligned
    const int tid = threadIdx.x;
    const int row0 = blockIdx.x * 4;
    const int b = row0 >> 10;            // block never crosses a batch
    const float* vb = verts + b * 3072;

    for (int n = tid; n < 1024; n += 256) {
        float x = vb[3 * n], y = vb[3 * n + 1], z = vb[3 * n + 2];
        float s = __fadd_rn(__fadd_rn(__fmul_rn(x, x), __fmul_rn(y, y)),
                            __fmul_rn(z, z));
        vps[n] = make_float4(x, y, z, s);
    }
    __syncthreads();

    const int w = tid >> 6, lane = tid & 63;
    const int row = row0 + w;
    const int n_i = row & 1023;
    const float4 pi = vps[n_i];
    const float xi = pi.x, yi = pi.y, zi = pi.z, sqi = pi.w;

    u64 K[16];
    u64 m1 = ~0ULL, m2 = ~0ULL;          // per-lane two smallest
#pragma unroll
    for (int t = 0; t < 16; ++t) {
        int j = t * 64 + lane;
        float4 p = vps[j];
        float dot = __fadd_rn(__fadd_rn(__fmul_rn(xi, p.x),
                                        __fmul_rn(yi, p.y)),
                              __fmul_rn(zi, p.z));
        float d = __fsub_rn(__fadd_rn(sqi, p.w), __fmul_rn(2.0f, dot));
        d = __fadd_rn(d, 0.0f);          // canonicalize -0.0 -> +0.0
        unsigned u = __float_as_uint(d);
        unsigned m = (u & 0x80000000u) ? ~u : (u | 0x80000000u);
        u64 k = ((u64)m << 10) | (unsigned)j;
        K[t] = k;
        bool lt1 = k < m1;
        u64 nm2 = lt1 ? m1 : ((k < m2) ? k : m2);
        m1 = lt1 ? k : m1;
        m2 = nm2;
    }

    // wave-max(m2) and wave-min(m1)
    u64 tmax = m2, tmin = m1;
#pragma unroll
    for (int off = 1; off < 64; off <<= 1) {
        u64 a = __shfl_xor(tmax, off); if (a > tmax) tmax = a;
        u64 c = __shfl_xor(tmin, off); if (c < tmin) tmin = c;
    }

    // count at T = tmax (guaranteed >= 127); bisect down to <= 192
    u64 T = tmax;
    int chi;
    {
        int c = 0;
#pragma unroll
        for (int t = 0; t < 16; ++t) c += (K[t] < T) ? 1 : 0;
#pragma unroll
        for (int off = 1; off < 64; off <<= 1) c += __shfl_xor(c, off);
        chi = c;
    }
    u64 lo = tmin, hi = T;
    while (chi > 192) {
        u64 mid = (lo + hi) >> 1;
        int c = 0;
#pragma unroll
        for (int t = 0; t < 16; ++t) c += (K[t] < mid) ? 1 : 0;
#pragma unroll
        for (int off = 1; off < 64; off <<= 1) c += __shfl_xor(c, off);
        if (c >= 101) { hi = mid; chi = c; } else lo = mid;
    }
    T = hi;
    const int n = chi;                   // 101 <= n <= 192

    // compact candidates < T via wave prefix-scan
    int myc_n = 0;
#pragma unroll
    for (int t = 0; t < 16; ++t) myc_n += (K[t] < T) ? 1 : 0;
    int sc = myc_n;
#pragma unroll
    for (int off = 1; off < 64; off <<= 1) {
        int v = __shfl_up(sc, off);
        if (lane >= off) sc += v;
    }
    int pos = sc - myc_n;
#pragma unroll
    for (int t = 0; t < 16; ++t) {
        if (K[t] < T) cand[w][pos++] = K[t];
    }
    if (lane == 0) cand[w][n] = ~0ULL;   // sentinel for b128 pair tail
    __syncthreads();

    // exact ranks within compacted set (pairs via b128)
    u64 myc[3]; int rk[3];
#pragma unroll
    for (int q = 0; q < 3; ++q) {
        int i = lane + q * 64;
        myc[q] = (i < n) ? cand[w][i] : ~0ULL;
        rk[q] = 0;
    }
    {
        const ulonglong2* c2 = (const ulonglong2*)&cand[w][0];
        const int half = (n + 1) >> 1;
        for (int jj = 0; jj < half; ++jj) {
            ulonglong2 kk = c2[jj];
#pragma unroll
            for (int q = 0; q < 3; ++q) {
                rk[q] += (kk.x < myc[q]) ? 1 : 0;
                rk[q] += (kk.y < myc[q]) ? 1 : 0;
            }
        }
    }

    // write ranks 1..100 (float4) to global AND LDS (aliasing cand[w] -
    // wave-private region; within-wave LDS ops are ordered)
    const int rowbase = row & ~1023;
    float4* nd4w = (float4*)&cand[w][0];
#pragma unroll
    for (int q = 0; q < 3; ++q) {
        int i = lane + q * 64;
        if (i < n) {
            int r = rk[q];
            if (r >= 1 && r <= 100) {
                int slot = r - 1;
                unsigned j = (unsigned)(myc[q] & 1023u);
                idx_out[row * 100 + slot] = rowbase + (int)j;
                float4 pj = vps[j];
                float dx = pj.x - xi, dy = pj.y - yi, dz = pj.z - zi;
                float nrm = sqrtf(__fadd_rn(__fadd_rn(__fmul_rn(dx, dx),
                                                      __fmul_rn(dy, dy)),
                                            __fmul_rn(dz, dz)));
                float inv = 1.0f / fmaxf(nrm, 1e-12f);
                float4 nv = make_float4(dx * inv, dy * inv, dz * inv, 0.0f);
                nd_out[row * 100 + slot] = nv;
                nd4w[slot] = nv;
            }
        }
    }
    __syncthreads();

    // ---- fused surface conv for the block's 4 rows ----
    const int d = tid & 127;
    float lx = dl[d], ly = dl[128 + d], lz = dl[256 + d];
    float li = 1.0f / fmaxf(sqrtf((lx * lx + ly * ly) + lz * lz), 1e-12f);
    lx *= li; ly *= li; lz *= li;
    float mx = dm[d], my = dm[128 + d], mz = dm[256 + d];
    float mi = 1.0f / fmaxf(sqrtf((mx * mx + my * my) + mz * mz), 1e-12f);
    mx *= mi; my *= mi; mz *= mi;
    float gx = dg[d], gy = dg[128 + d], gz = dg[256 + d];
    float gi = 1.0f / fmaxf(sqrtf((gx * gx + gy * gy) + gz * gz), 1e-12f);
    gx *= gi; gy *= gi; gz *= gi;

#pragma unroll
    for (int p = 0; p < 2; ++p) {
        int rr = (tid >> 7) + 2 * p;     // wave-uniform
        const float4* ns = (const float4*)&cand[rr][0];
        float ml = -1e30f, mm = -1e30f, mg = -1e30f;
        int k = 0;
        for (; k < 5; ++k) {
            float4 v = ns[k];
            ml = fmaxf(ml, (v.x * lx + v.y * ly) + v.z * lz);
            mm = fmaxf(mm, (v.x * mx + v.y * my) + v.z * mz);
            mg = fmaxf(mg, (v.x * gx + v.y * gy) + v.z * gz);
        }
        for (; k < 20; ++k) {
            float4 v = ns[k];
            mm = fmaxf(mm, (v.x * mx + v.y * my) + v.z * mz);
            mg = fmaxf(mg, (v.x * gx + v.y * gy) + v.z * gz);
        }
        for (; k < 100; ++k) {
            float4 v = ns[k];
            mg = fmaxf(mg, (v.x * gx + v.y * gy) + v.z * gz);
        }
        int orow = row0 + rr;
        raw_l[orow * 128 + d] = fmaxf(ml, 0.0f);
        raw_m[orow * 128 + d] = fmaxf(mm, 0.0f);
        raw_g[orow * 128 + d] = fmaxf(mg, 0.0f);
    }

    // ---- W -> two-plane fragment-ordered split-bf16 (independent tail) ----
    {
        const int gid = blockIdx.x * 256 + tid;
        conv_wfrag(Wm1, wh_m1, wl_m1, 4, gid, 262144);
        conv_wfrag(Wg1, wh_g1, wl_g1, 4, gid, 262144);
        conv_wfrag(Wg2, wh_g2, wl_g2, 4, gid, 262144);
        conv_wfrag(Wdn, wh_dn, wl_dn, 12, gid, 262144);
    }
}

// ---------------------------------------------------------------------------
// Kernel 2: BN partial sums: 64 blocks per tensor (64 rows each), coalesced,
// fp64, deterministic. (unchanged)
// ---------------------------------------------------------------------------
__global__ __launch_bounds__(256) void bnsum_kernel(
    const float* s0, double* p0,
    const float* s1, double* p1,
    const float* s2, double* p2)
{
    const int t = blockIdx.x >> 6;
    const int blk = blockIdx.x & 63;
    const float* src = (t == 0) ? s0 : (t == 1) ? s1 : s2;
    double* p = (t == 0) ? p0 : (t == 1) ? p1 : p2;
    const int tid = threadIdx.x;
    const int c = tid & 127, seg = tid >> 7;    // 2 segs x 32 rows
    const float* q = src + ((size_t)blk * 64 + seg * 32) * 128 + c;
    double s = 0.0, ss = 0.0;
    for (int r = 0; r < 32; ++r) { float v = q[r * 128]; s += v; ss += (double)v * v; }
    __shared__ double Ls[2][128], Lq[2][128];
    Ls[seg][c] = s; Lq[seg][c] = ss;
    __syncthreads();
    if (tid < 128) {
        p[blk * 256 + c]       = Ls[0][c] + Ls[1][c];
        p[blk * 256 + 128 + c] = Lq[0][c] + Lq[1][c];
    }
}

// st from partials: a = g/sqrt(var+eps), b2 = e - m*a (fp64, deterministic)
__device__ __forceinline__ void compute_st(const double* __restrict__ p,
                                           const float* __restrict__ g,
                                           const float* __restrict__ e,
                                           float* stA, float* stB,
                                           int tid, int nthreads)
{
    for (int c = tid; c < 128; c += nthreads) {
        double S = 0.0, Q = 0.0;
#pragma unroll
        for (int bb = 0; bb < 64; ++bb) { S += p[bb * 256 + c]; Q += p[bb * 256 + 128 + c]; }
        double m = S * (1.0 / 4096.0);
        double var = Q * (1.0 / 4096.0) - m * m;
        double a = (double)g[c] / sqrt(var + 1e-5);
        stA[c] = (float)a;
        stB[c] = (float)((double)e[c] - m * a);
    }
}

// ---------------------------------------------------------------------------
// Kernel 3: dual-job GEMM (CIN=128) via split-bf16 MFMA, two-plane storage.
// Block tile: 16 rows x 128 cols, 256 threads = 4 waves x 2 col-tiles.
// grid (256 rowtiles, 2 colhalves, jobs). A staged bn_relu'd to LDS as
// separate hi/lo bf16 planes (stride 136 shorts = 16B-aligned rows);
// W read pre-fragmented two-plane from global. Every fragment is one 16B
// load in register order -> ZERO unpack VALU in the hot loop.
// 3 MFMAs per k-step: ah*bh + al*bh + ah*bl (al*bl ~2^-18, dropped).
// ---------------------------------------------------------------------------
__global__ __launch_bounds__(256) void gemm2_kernel(
    const float* __restrict__ Aa, const double* __restrict__ pa,
    const float* __restrict__ ga, const float* __restrict__ ea,
    const unsigned short* __restrict__ Wha, const unsigned short* __restrict__ Wla,
    const float* __restrict__ ba, float* __restrict__ outa,
    const float* __restrict__ Ab, const double* __restrict__ pb,
    const float* __restrict__ gb, const float* __restrict__ eb,
    const unsigned short* __restrict__ Whb, const unsigned short* __restrict__ Wlb,
    const float* __restrict__ bb, float* __restrict__ outb)
{
    const int job = blockIdx.z;
    const float* A = job ? Ab : Aa;  const double* p = job ? pb : pa;
    const float* g = job ? gb : ga;  const float* e = job ? eb : ea;
    const unsigned short* Wh = job ? Whb : Wha;
    const unsigned short* Wl = job ? Wlb : Wla;
    const float* bias = job ? bb : ba;
    float* out = job ? outb : outa;

    __shared__ float stA[128], stB[128];
    __shared__ __align__(16) unsigned short Ah[16 * 136];  // 4.25 KB hi-plane
    __shared__ __align__(16) unsigned short Alo[16 * 136]; // 4.25 KB lo-plane
    const int tid = threadIdx.x;
    const int r0 = blockIdx.x * 16;

    compute_st(p, g, e, stA, stB, tid, 256);
    __syncthreads();

    for (int t = tid; t < 16 * 128; t += 256) {
        int r = t >> 7, c = t & 127;
        float v = fmaxf(fmaf(stA[c], A[(size_t)(r0 + r) * 128 + c], stB[c]), 0.0f);
        unsigned pk = splitpack(v);
        Ah[r * 136 + c]  = (unsigned short)pk;
        Alo[r * 136 + c] = (unsigned short)(pk >> 16);
    }
    __syncthreads();

    const int lane = tid & 63, wv = tid >> 6;
    const int ct0 = blockIdx.y * 8 + wv * 2;
    const int col0 = ct0 * 16 + (lane & 15);
    const float bz0 = bias[col0], bz1 = bias[col0 + 16];
    ffrag acc0 = {bz0, bz0, bz0, bz0};
    ffrag acc1 = {bz1, bz1, bz1, bz1};

    const int aoff = (lane & 15) * 136 + (lane >> 4) * 8;

#pragma unroll
    for (int kb = 0; kb < 4; ++kb) {
        bfrag ah = *(const bfrag*)(Ah + aoff + kb * 32);
        bfrag al = *(const bfrag*)(Alo + aoff + kb * 32);
        {
            size_t bi = ((size_t)(ct0 * 4 + kb) * 64 + lane) * 8;
            bfrag bh = *(const bfrag*)(Wh + bi);
            bfrag bl = *(const bfrag*)(Wl + bi);
            acc0 = __builtin_amdgcn_mfma_f32_16x16x32_bf16(ah, bh, acc0, 0, 0, 0);
            acc0 = __builtin_amdgcn_mfma_f32_16x16x32_bf16(al, bh, acc0, 0, 0, 0);
            acc0 = __builtin_amdgcn_mfma_f32_16x16x32_bf16(ah, bl, acc0, 0, 0, 0);
        }
        {
            size_t bi = ((size_t)((ct0 + 1) * 4 + kb) * 64 + lane) * 8;
            bfrag bh = *(const bfrag*)(Wh + bi);
            bfrag bl = *(const bfrag*)(Wl + bi);
            acc1 = __builtin_amdgcn_mfma_f32_16x16x32_bf16(ah, bh, acc1, 0, 0, 0);
            acc1 = __builtin_amdgcn_mfma_f32_16x16x32_bf16(al, bh, acc1, 0, 0, 0);
            acc1 = __builtin_amdgcn_mfma_f32_16x16x32_bf16(ah, bl, acc1, 0, 0, 0);
        }
    }

    const int rowb = r0 + (lane >> 4) * 4;     // verified C/D layout [m89/m91]
#pragma unroll
    for (int j = 0; j < 4; ++j) {
        out[(size_t)(rowb + j) * 256 + col0]      = acc0[j];
        out[(size_t)(rowb + j) * 256 + col0 + 16] = acc1[j];
    }
}

// ---------------------------------------------------------------------------
// Kernel 4: conv-layer apply (unchanged round-6 body)
// ---------------------------------------------------------------------------
__global__ __launch_bounds__(128) void layer_kernel(
    const float4* __restrict__ nd, const int* __restrict__ idxbuf,
    const float* dir0, const float* fo0, float* out0, int K0,
    const float* dir1, const float* fo1, float* out1, int K1)
{
    const int job = blockIdx.y;
    const float* dirs = job ? dir1 : dir0;
    const float* fo = job ? fo1 : fo0;
    float* out = job ? out1 : out0;
    const int K = job ? K1 : K0;

    const int d = threadIdx.x;
    const int row = blockIdx.x;

    float dx = dirs[d], dy = dirs[128 + d], dz = dirs[256 + d];
    float di = 1.0f / fmaxf(sqrtf((dx * dx + dy * dy) + dz * dz), 1e-12f);
    dx *= di; dy *= di; dz *= di;

    const float4* ns = nd + (size_t)row * 100;
    const int* ib = idxbuf + (size_t)row * 100;

    float acc = -1e30f;
    for (int k4 = 0; k4 < K; k4 += 4) {
        int4 ix4 = *(const int4*)&ib[k4];
        float fs0 = fo[(size_t)ix4.x * 256 + 128 + d];
        float fs1 = fo[(size_t)ix4.y * 256 + 128 + d];
        float fs2 = fo[(size_t)ix4.z * 256 + 128 + d];
        float fs3 = fo[(size_t)ix4.w * 256 + 128 + d];
        float4 v0 = ns[k4 + 0];
        float4 v1 = ns[k4 + 1];
        float4 v2 = ns[k4 + 2];
        float4 v3 = ns[k4 + 3];
        float t0 = fmaxf((v0.x * dx + v0.y * dy) + v0.z * dz, 0.0f);
        float t1 = fmaxf((v1.x * dx + v1.y * dy) + v1.z * dz, 0.0f);
        float t2 = fmaxf((v2.x * dx + v2.y * dy) + v2.z * dz, 0.0f);
        float t3 = fmaxf((v3.x * dx + v3.y * dy) + v3.z * dz, 0.0f);
        acc = fmaxf(acc, t0 * fs0);
        acc = fmaxf(acc, t1 * fs1);
        acc = fmaxf(acc, t2 * fs2);
        acc = fmaxf(acc, t3 * fs3);
    }
    out[row * 128 + d] = fo[row * 256 + d] + acc;
}

// ---------------------------------------------------------------------------
// Kernel 5: final GEMM (CIN=384) via split-bf16 MFMA, two-plane storage,
// same structure as gemm2 (16x128 block tile, grid (256,2)), 3 A-segments,
// final relu. A-plane stride 392 shorts (16B-aligned rows).
// ---------------------------------------------------------------------------
__global__ __launch_bounds__(256) void gemmf_kernel(
    const float* __restrict__ A0, const double* __restrict__ p0,
    const float* __restrict__ g0, const float* __restrict__ e0,
    const float* __restrict__ A1, const double* __restrict__ p1,
    const float* __restrict__ g1, const float* __restrict__ e1,
    const float* __restrict__ A2, const double* __restrict__ p2,
    const float* __restrict__ g2, const float* __restrict__ e2,
    const unsigned short* __restrict__ Wh, const unsigned short* __restrict__ Wl,
    const float* __restrict__ bias, float* __restrict__ out)
{
    __shared__ float stA[384], stB[384];
    __shared__ __align__(16) unsigned short Ah[16 * 392];  // 12.25 KB
    __shared__ __align__(16) unsigned short Alo[16 * 392]; // 12.25 KB
    const int tid = threadIdx.x;
    const int r0 = blockIdx.x * 16;

    compute_st(p0, g0, e0, stA,       stB,       tid, 256);
    compute_st(p1, g1, e1, stA + 128, stB + 128, tid, 256);
    compute_st(p2, g2, e2, stA + 256, stB + 256, tid, 256);
    __syncthreads();

    for (int t = tid; t < 16 * 384; t += 256) {
        int r = t / 384, c = t - r * 384;
        int seg = c >> 7, cc = c & 127;
        const float* A = (seg == 0) ? A0 : (seg == 1) ? A1 : A2;
        float v = fmaxf(fmaf(stA[c], A[(size_t)(r0 + r) * 128 + cc], stB[c]), 0.0f);
        unsigned pk = splitpack(v);
        Ah[r * 392 + c]  = (unsigned short)pk;
        Alo[r * 392 + c] = (unsigned short)(pk >> 16);
    }
    __syncthreads();

    const int lane = tid & 63, wv = tid >> 6;
    const int ct0 = blockIdx.y * 8 + wv * 2;
    const int col0 = ct0 * 16 + (lane & 15);
    const float bz0 = bias[col0], bz1 = bias[col0 + 16];
    ffrag acc0 = {bz0, bz0, bz0, bz0};
    ffrag acc1 = {bz1, bz1, bz1, bz1};

    const int aoff = (lane & 15) * 392 + (lane >> 4) * 8;

#pragma unroll
    for (int kb = 0; kb < 12; ++kb) {
        bfrag ah = *(const bfrag*)(Ah + aoff + kb * 32);
        bfrag al = *(const bfrag*)(Alo + aoff + kb * 32);
        {
            size_t bi = ((size_t)(ct0 * 12 + kb) * 64 + lane) * 8;
            bfrag bh = *(const bfrag*)(Wh + bi);
            bfrag bl = *(const bfrag*)(Wl + bi);
            acc0 = __builtin_amdgcn_mfma_f32_16x16x32_bf16(ah, bh, acc0, 0, 0, 0);
            acc0 = __builtin_amdgcn_mfma_f32_16x16x32_bf16(al, bh, acc0, 0, 0, 0);
            acc0 = __builtin_amdgcn_mfma_f32_16x16x32_bf16(ah, bl, acc0, 0, 0, 0);
        }
        {
            size_t bi = ((size_t)((ct0 + 1) * 12 + kb) * 64 + lane) * 8;
            bfrag bh = *(const bfrag*)(Wh + bi);
            bfrag bl = *(const bfrag*)(Wl + bi);
            acc1 = __builtin_amdgcn_mfma_f32_16x16x32_bf16(ah, bh, acc1, 0, 0, 0);
            acc1 = __builtin_amdgcn_mfma_f32_16x16x32_bf16(al, bh, acc1, 0, 0, 0);
            acc1 = __builtin_amdgcn_mfma_f32_16x16x32_bf16(ah, bl, acc1, 0, 0, 0);
        }
    }

    const int rowb = r0 + (lane >> 4) * 4;     // verified C/D layout [m89/m91]
#pragma unroll
    for (int j = 0; j < 4; ++j) {
        out[(size_t)(rowb + j) * 256 + col0]      = fmaxf(acc0[j], 0.0f);
        out[(size_t)(rowb + j) * 256 + col0 + 16] = fmaxf(acc1[j], 0.0f);
    }
}

// ---------------------------------------------------------------------------
extern "C" void kernel_launch(void* const* d_in, const int* in_sizes, int n_in,
                              void* d_out, int out_size, void* d_ws, size_t ws_size,
                              hipStream_t stream)
{
    (void)in_sizes; (void)n_in; (void)out_size; (void)ws_size;

    const float* verts   = (const float*)d_in[0];
    const float* dirs_l  = (const float*)d_in[1];
    const float* dirs_m0 = (const float*)d_in[2];
    const float* W_m1    = (const float*)d_in[3];
    const float* b_m1    = (const float*)d_in[4];
    const float* dirs_m1 = (const float*)d_in[5];
    const float* dirs_g0 = (const float*)d_in[6];
    const float* W_g1    = (const float*)d_in[7];
    const float* b_g1    = (const float*)d_in[8];
    const float* dirs_g1 = (const float*)d_in[9];
    const float* W_g2    = (const float*)d_in[10];
    const float* b_g2    = (const float*)d_in[11];
    const float* dirs_g2 = (const float*)d_in[12];
    const float* g_l  = (const float*)d_in[13]; const float* be_l  = (const float*)d_in[14];
    const float* g_m0 = (const float*)d_in[15]; const float* be_m0 = (const float*)d_in[16];
    const float* g_m1 = (const float*)d_in[17]; const float* be_m1 = (const float*)d_in[18];
    const float* g_g0 = (const float*)d_in[19]; const float* be_g0 = (const float*)d_in[20];
    const float* g_g1 = (const float*)d_in[21]; const float* be_g1 = (const float*)d_in[22];
    const float* g_g2 = (const float*)d_in[23]; const float* be_g2 = (const float*)d_in[24];
    const float* W_down = (const float*)d_in[25];
    const float* b_down = (const float*)d_in[26];

    char* ws = (char*)d_ws;
    const size_t MB = 1 << 20;
    int*    idx100 = (int*)   (ws + 0);               // 1.64 MB
    double* p_l    = (double*)(ws + 2 * MB);          // 6 x 128 KB fp64 partials
    double* p_m0   = p_l  + 32768;
    double* p_m1   = p_m0 + 32768;
    double* p_g0   = p_m1 + 32768;
    double* p_g1   = p_g0 + 32768;
    double* p_g2   = p_g1 + 32768;
    float4* nd100  = (float4*)(ws + 4 * MB);          // 6.55 MB (stride-4)
    float* raw_l  = (float*)(ws + 11 * MB);           // 2 MB each
    float* raw_m0 = (float*)(ws + 13 * MB);
    float* raw_g0 = (float*)(ws + 15 * MB);
    float* raw_m1 = (float*)(ws + 17 * MB);
    float* raw_g1 = (float*)(ws + 19 * MB);
    float* raw_g2 = (float*)(ws + 21 * MB);
    float* fo_m   = (float*)(ws + 23 * MB);           // 4 MB each
    float* fo_g   = (float*)(ws + 27 * MB);
    float* fo_g2  = (float*)(ws + 31 * MB);
    unsigned short* wh_m1 = (unsigned short*)(ws + 36 * MB);            // 64 KB
    unsigned short* wl_m1 = (unsigned short*)(ws + 36 * MB + 0x10000);  // 64 KB
    unsigned short* wh_g1 = (unsigned short*)(ws + 37 * MB);
    unsigned short* wl_g1 = (unsigned short*)(ws + 37 * MB + 0x10000);
    unsigned short* wh_g2 = (unsigned short*)(ws + 38 * MB);
    unsigned short* wl_g2 = (unsigned short*)(ws + 38 * MB + 0x10000);
    unsigned short* wh_dn = (unsigned short*)(ws + 39 * MB);            // 192 KB
    unsigned short* wl_dn = (unsigned short*)(ws + 39 * MB + 0x30000);  // 192 KB

    // L1. KNN + nd + fused surface convs + W->two-plane split-bf16 fragments
    knnsurf_kernel<<<1024, 256, 0, stream>>>(verts, idx100, nd100,
                                             dirs_l, dirs_m0, dirs_g0,
                                             raw_l, raw_m0, raw_g0,
                                             W_m1, W_g1, W_g2, W_down,
                                             wh_m1, wl_m1, wh_g1, wl_g1,
                                             wh_g2, wl_g2, wh_dn, wl_dn);
    // L2. BN partials for l, m0, g0
    bnsum_kernel<<<192, 256, 0, stream>>>(raw_l, p_l, raw_m0, p_m0, raw_g0, p_g0);
    // L3. fo_m = bn_relu(raw_m0) @ W_m1 ; fo_g = bn_relu(raw_g0) @ W_g1  (MFMA)
    gemm2_kernel<<<dim3(256, 2, 2), 256, 0, stream>>>(
        raw_m0, p_m0, g_m0, be_m0, wh_m1, wl_m1, b_m1, fo_m,
        raw_g0, p_g0, g_g0, be_g0, wh_g1, wl_g1, b_g1, fo_g);
    // L4. conv-layer apply (m1: K=20, g1: K=100)
    layer_kernel<<<dim3(4096, 2), 128, 0, stream>>>(nd100, idx100,
                                                    dirs_m1, fo_m, raw_m1, 20,
                                                    dirs_g1, fo_g, raw_g1, 100);
    // L5. BN partials for m1, g1
    bnsum_kernel<<<128, 256, 0, stream>>>(raw_m1, p_m1, raw_g1, p_g1, raw_g1, p_g1);
    // L6. fo_g2 = bn_relu(raw_g1) @ W_g2  (MFMA)
    gemm2_kernel<<<dim3(256, 2, 1), 256, 0, stream>>>(
        raw_g1, p_g1, g_g1, be_g1, wh_g2, wl_g2, b_g2, fo_g2,
        raw_g1, p_g1, g_g1, be_g1, wh_g2, wl_g2, b_g2, fo_g2);
    // L7. conv-layer apply (g2: K=100)
    layer_kernel<<<dim3(4096, 1), 128, 0, stream>>>(nd100, idx100,
                                                    dirs_g2, fo_g2, raw_g2, 100,
                                                    dirs_g2, fo_g2, raw_g2, 100);
    // L8. BN partials for g2
    bnsum_kernel<<<64, 256, 0, stream>>>(raw_g2, p_g2, raw_g2, p_g2, raw_g2, p_g2);
    // L9. final: relu(concat(bn_relu each) @ W_down + b_down) -> fp32 out (MFMA)
    gemmf_kernel<<<dim3(256, 2), 256, 0, stream>>>(raw_l, p_l, g_l, be_l,
                                                   raw_m1, p_m1, g_m1, be_m1,
                                                   raw_g2, p_g2, g_g2, be_g2,
                                                   wh_dn, wl_dn, b_down, (float*)d_out);
}

// Round 14
// 237.580 us; speedup vs baseline: 1.0259x; 1.0259x over previous
//
#include <hip/hip_runtime.h>
#include <math.h>

typedef unsigned long long u64;
typedef __attribute__((ext_vector_type(8))) short bfrag;   // 8 bf16 (guide §3 verified typedef)
typedef __attribute__((ext_vector_type(4))) float ffrag;   // 4 fp32 accumulator

// ---------------------------------------------------------------------------
// split fp32 -> (hi,lo) bf16 pair packed in one dword (hi in low 16 bits).
// hi = truncation; residual is exact (Sterbenz); lo = RNE(residual).
// hi+lo represents x to ~2^-17 relative -> split-bf16 GEMM ~ fp32 accurate.
// ---------------------------------------------------------------------------
__device__ __forceinline__ unsigned splitpack(float x)
{
    unsigned u = __float_as_uint(x);
    unsigned hi = u >> 16;
    float r = x - __uint_as_float(hi << 16);
    unsigned v = __float_as_uint(r);
    unsigned lo = (v + 0x7FFFu + ((v >> 16) & 1u)) >> 16;
    return hi | (lo << 16);
}

// ---------------------------------------------------------------------------
// Convert W (K x 256 row-major fp32) to MFMA-fragment-ordered split-bf16:
// dword f = ((ct*KB + kb)*64 + lane)*8 + i holds
//   W[kb*32 + (lane>>4)*8 + i][ct*16 + (lane&15)]   (KB = K/32)
// The SAME (lane,elem)->k mapping is used for A fragments, so any hardware
// k-permutation cancels in the summed dot product. lane&15 = N index (must
// match HW; universal CDNA property).
// ---------------------------------------------------------------------------
__device__ void conv_wfrag(const float* __restrict__ W, unsigned* __restrict__ dst,
                           int KB, int gid, int stride)
{
    int total = KB * 32 * 256;
    for (int f = gid; f < total; f += stride) {
        int i = f & 7;
        int l = (f >> 3) & 63;
        int t = f >> 9;
        int kb = t % KB, ct = t / KB;
        int k = kb * 32 + (l >> 4) * 8 + i;
        int n = ct * 16 + (l & 15);
        dst[f] = splitpack(W[k * 256 + n]);
    }
}

// unpack 8 packed dwords -> hi-bf16 vector and lo-bf16 vector
#define UNPK8(H, L, q0, q1)                                                         \
    H[0] = (short)(q0.x); L[0] = (short)(q0.x >> 16);                               \
    H[1] = (short)(q0.y); L[1] = (short)(q0.y >> 16);                               \
    H[2] = (short)(q0.z); L[2] = (short)(q0.z >> 16);                               \
    H[3] = (short)(q0.w); L[3] = (short)(q0.w >> 16);                               \
    H[4] = (short)(q1.x); L[4] = (short)(q1.x >> 16);                               \
    H[5] = (short)(q1.y); L[5] = (short)(q1.y >> 16);                               \
    H[6] = (short)(q1.z); L[6] = (short)(q1.z >> 16);                               \
    H[7] = (short)(q1.w); L[7] = (short)(q1.w >> 16);

// ---------------------------------------------------------------------------
// Kernel 1: KNN (bit-exact vs np/fp32 reference) + fused 3-scale surface conv.
// One wave per row, 4 rows per 256-thread block. LDS ~22.7 KB. (round-0 body)
// NEW tail: converts the 4 W matrices to fragment-ordered split-bf16 (runs
// before any GEMM dispatch; ~1 element/thread).
// ---------------------------------------------------------------------------
__global__ __launch_bounds__(256) void knnsurf_kernel(
    const float* __restrict__ verts,
    int* __restrict__ idx_out, float4* __restrict__ nd_out,
    const float* __restrict__ dl, const float* __restrict__ dm,
    const float* __restrict__ dg,
    float* __restrict__ raw_l, float* __restrict__ raw_m, float* __restrict__ raw_g,
    const float* __restrict__ Wm1, const float* __restrict__ Wg1,
    const float* __restrict__ Wg2, const float* __restrict__ Wdn,
    unsigned* __restrict__ wf_m1, unsigned* __restrict__ wf_g1,
    unsigned* __restrict__ wf_g2, unsigned* __restrict__ wf_dn)
{
    __shared__ float4 vps[1024];                    // x,y,z,sq  (16 KB)
    __shared__ __align__(16) u64 cand[4][208];      // 6.7 KB; row = 16B-aligned
    const int tid = threadIdx.x;
    const int row0 = blockIdx.x * 4;
    const int b = row0 >> 10;            // block never crosses a batch
    const float* vb = verts + b * 3072;

    for (int n = tid; n < 1024; n += 256) {
        float x = vb[3 * n], y = vb[3 * n + 1], z = vb[3 * n + 2];
        float s = __fadd_rn(__fadd_rn(__fmul_rn(x, x), __fmul_rn(y, y)),
                            __fmul_rn(z, z));
        vps[n] = make_float4(x, y, z, s);
    }
    __syncthreads();

    const int w = tid >> 6, lane = tid & 63;
    const int row = row0 + w;
    const int n_i = row & 1023;
    const float4 pi = vps[n_i];
    const float xi = pi.x, yi = pi.y, zi = pi.z, sqi = pi.w;

    u64 K[16];
    u64 m1 = ~0ULL, m2 = ~0ULL;          // per-lane two smallest
#pragma unroll
    for (int t = 0; t < 16; ++t) {
        int j = t * 64 + lane;
        float4 p = vps[j];
        float dot = __fadd_rn(__fadd_rn(__fmul_rn(xi, p.x),
                                        __fmul_rn(yi, p.y)),
                              __fmul_rn(zi, p.z));
        float d = __fsub_rn(__fadd_rn(sqi, p.w), __fmul_rn(2.0f, dot));
        d = __fadd_rn(d, 0.0f);          // canonicalize -0.0 -> +0.0
        unsigned u = __float_as_uint(d);
        unsigned m = (u & 0x80000000u) ? ~u : (u | 0x80000000u);
        u64 k = ((u64)m << 10) | (unsigned)j;
        K[t] = k;
        bool lt1 = k < m1;
        u64 nm2 = lt1 ? m1 : ((k < m2) ? k : m2);
        m1 = lt1 ? k : m1;
        m2 = nm2;
    }

    // wave-max(m2) and wave-min(m1)
    u64 tmax = m2, tmin = m1;
#pragma unroll
    for (int off = 1; off < 64; off <<= 1) {
        u64 a = __shfl_xor(tmax, off); if (a > tmax) tmax = a;
        u64 c = __shfl_xor(tmin, off); if (c < tmin) tmin = c;
    }

    // count at T = tmax (guaranteed >= 127); bisect down to <= 192
    u64 T = tmax;
    int chi;
    {
        int c = 0;
#pragma unroll
        for (int t = 0; t < 16; ++t) c += (K[t] < T) ? 1 : 0;
#pragma unroll
        for (int off = 1; off < 64; off <<= 1) c += __shfl_xor(c, off);
        chi = c;
    }
    u64 lo = tmin, hi = T;
    while (chi > 192) {
        u64 mid = (lo + hi) >> 1;
        int c = 0;
#pragma unroll
        for (int t = 0; t < 16; ++t) c += (K[t] < mid) ? 1 : 0;
#pragma unroll
        for (int off = 1; off < 64; off <<= 1) c += __shfl_xor(c, off);
        if (c >= 101) { hi = mid; chi = c; } else lo = mid;
    }
    T = hi;
    const int n = chi;                   // 101 <= n <= 192

    // compact candidates < T via wave prefix-scan
    int myc_n = 0;
#pragma unroll
    for (int t = 0; t < 16; ++t) myc_n += (K[t] < T) ? 1 : 0;
    int sc = myc_n;
#pragma unroll
    for (int off = 1; off < 64; off <<= 1) {
        int v = __shfl_up(sc, off);
        if (lane >= off) sc += v;
    }
    int pos = sc - myc_n;
#pragma unroll
    for (int t = 0; t < 16; ++t) {
        if (K[t] < T) cand[w][pos++] = K[t];
    }
    if (lane == 0) cand[w][n] = ~0ULL;   // sentinel for b128 pair tail
    __syncthreads();

    // exact ranks within compacted set (pairs via b128)
    u64 myc[3]; int rk[3];
#pragma unroll
    for (int q = 0; q < 3; ++q) {
        int i = lane + q * 64;
        myc[q] = (i < n) ? cand[w][i] : ~0ULL;
        rk[q] = 0;
    }
    {
        const ulonglong2* c2 = (const ulonglong2*)&cand[w][0];
        const int half = (n + 1) >> 1;
        for (int jj = 0; jj < half; ++jj) {
            ulonglong2 kk = c2[jj];
#pragma unroll
            for (int q = 0; q < 3; ++q) {
                rk[q] += (kk.x < myc[q]) ? 1 : 0;
                rk[q] += (kk.y < myc[q]) ? 1 : 0;
            }
        }
    }

    // write ranks 1..100 (float4) to global AND LDS (aliasing cand[w] -
    // wave-private region; within-wave LDS ops are ordered)
    const int rowbase = row & ~1023;
    float4* nd4w = (float4*)&cand[w][0];
#pragma unroll
    for (int q = 0; q < 3; ++q) {
        int i = lane + q * 64;
        if (i < n) {
            int r = rk[q];
            if (r >= 1 && r <= 100) {
                int slot = r - 1;
                unsigned j = (unsigned)(myc[q] & 1023u);
                idx_out[row * 100 + slot] = rowbase + (int)j;
                float4 pj = vps[j];
                float dx = pj.x - xi, dy = pj.y - yi, dz = pj.z - zi;
                float nrm = sqrtf(__fadd_rn(__fadd_rn(__fmul_rn(dx, dx),
                                                      __fmul_rn(dy, dy)),
                                            __fmul_rn(dz, dz)));
                float inv = 1.0f / fmaxf(nrm, 1e-12f);
                float4 nv = make_float4(dx * inv, dy * inv, dz * inv, 0.0f);
                nd_out[row * 100 + slot] = nv;
                nd4w[slot] = nv;
            }
        }
    }
    __syncthreads();

    // ---- fused surface conv for the block's 4 rows ----
    const int d = tid & 127;
    float lx = dl[d], ly = dl[128 + d], lz = dl[256 + d];
    float li = 1.0f / fmaxf(sqrtf((lx * lx + ly * ly) + lz * lz), 1e-12f);
    lx *= li; ly *= li; lz *= li;
    float mx = dm[d], my = dm[128 + d], mz = dm[256 + d];
    float mi = 1.0f / fmaxf(sqrtf((mx * mx + my * my) + mz * mz), 1e-12f);
    mx *= mi; my *= mi; mz *= mi;
    float gx = dg[d], gy = dg[128 + d], gz = dg[256 + d];
    float gi = 1.0f / fmaxf(sqrtf((gx * gx + gy * gy) + gz * gz), 1e-12f);
    gx *= gi; gy *= gi; gz *= gi;

#pragma unroll
    for (int p = 0; p < 2; ++p) {
        int rr = (tid >> 7) + 2 * p;     // wave-uniform
        const float4* ns = (const float4*)&cand[rr][0];
        float ml = -1e30f, mm = -1e30f, mg = -1e30f;
        int k = 0;
        for (; k < 5; ++k) {
            float4 v = ns[k];
            ml = fmaxf(ml, (v.x * lx + v.y * ly) + v.z * lz);
            mm = fmaxf(mm, (v.x * mx + v.y * my) + v.z * mz);
            mg = fmaxf(mg, (v.x * gx + v.y * gy) + v.z * gz);
        }
        for (; k < 20; ++k) {
            float4 v = ns[k];
            mm = fmaxf(mm, (v.x * mx + v.y * my) + v.z * mz);
            mg = fmaxf(mg, (v.x * gx + v.y * gy) + v.z * gz);
        }
        for (; k < 100; ++k) {
            float4 v = ns[k];
            mg = fmaxf(mg, (v.x * gx + v.y * gy) + v.z * gz);
        }
        int orow = row0 + rr;
        raw_l[orow * 128 + d] = fmaxf(ml, 0.0f);
        raw_m[orow * 128 + d] = fmaxf(mm, 0.0f);
        raw_g[orow * 128 + d] = fmaxf(mg, 0.0f);
    }

    // ---- W -> fragment-ordered split-bf16 (independent tail work) ----
    {
        const int gid = blockIdx.x * 256 + tid;
        conv_wfrag(Wm1, wf_m1, 4, gid, 262144);
        conv_wfrag(Wg1, wf_g1, 4, gid, 262144);
        conv_wfrag(Wg2, wf_g2, 4, gid, 262144);
        conv_wfrag(Wdn, wf_dn, 12, gid, 262144);
    }
}

// ---------------------------------------------------------------------------
// Kernel 2: BN partial sums: 64 blocks per tensor (64 rows each), coalesced,
// fp64, deterministic. (unchanged)
// ---------------------------------------------------------------------------
__global__ __launch_bounds__(256) void bnsum_kernel(
    const float* s0, double* p0,
    const float* s1, double* p1,
    const float* s2, double* p2)
{
    const int t = blockIdx.x >> 6;
    const int blk = blockIdx.x & 63;
    const float* src = (t == 0) ? s0 : (t == 1) ? s1 : s2;
    double* p = (t == 0) ? p0 : (t == 1) ? p1 : p2;
    const int tid = threadIdx.x;
    const int c = tid & 127, seg = tid >> 7;    // 2 segs x 32 rows
    const float* q = src + ((size_t)blk * 64 + seg * 32) * 128 + c;
    double s = 0.0, ss = 0.0;
    for (int r = 0; r < 32; ++r) { float v = q[r * 128]; s += v; ss += (double)v * v; }
    __shared__ double Ls[2][128], Lq[2][128];
    Ls[seg][c] = s; Lq[seg][c] = ss;
    __syncthreads();
    if (tid < 128) {
        p[blk * 256 + c]       = Ls[0][c] + Ls[1][c];
        p[blk * 256 + 128 + c] = Lq[0][c] + Lq[1][c];
    }
}

// st from partials: a = g/sqrt(var+eps), b2 = e - m*a (fp64, deterministic)
__device__ __forceinline__ void compute_st(const double* __restrict__ p,
                                           const float* __restrict__ g,
                                           const float* __restrict__ e,
                                           float* stA, float* stB,
                                           int tid, int nthreads)
{
    for (int c = tid; c < 128; c += nthreads) {
        double S = 0.0, Q = 0.0;
#pragma unroll
        for (int bb = 0; bb < 64; ++bb) { S += p[bb * 256 + c]; Q += p[bb * 256 + 128 + c]; }
        double m = S * (1.0 / 4096.0);
        double var = Q * (1.0 / 4096.0) - m * m;
        double a = (double)g[c] / sqrt(var + 1e-5);
        stA[c] = (float)a;
        stB[c] = (float)((double)e[c] - m * a);
    }
}

// ---------------------------------------------------------------------------
// Kernel 3: dual-job GEMM (CIN=128) via split-bf16 MFMA.
// Block tile: 16 rows x 128 cols, 256 threads = 4 waves x 2 col-tiles.
// grid (256 rowtiles, 2 colhalves, jobs). A staged bn_relu'd to LDS as packed
// hi/lo bf16; W read pre-fragmented from global (coalesced 32B/lane).
// 3 MFMAs per k-step: ah*bh + al*bh + ah*bl (al*bl ~2^-18, dropped).
// ---------------------------------------------------------------------------
__global__ __launch_bounds__(256) void gemm2_kernel(
    const float* __restrict__ Aa, const double* __restrict__ pa,
    const float* __restrict__ ga, const float* __restrict__ ea,
    const unsigned* __restrict__ Wfa, const float* __restrict__ ba, float* __restrict__ outa,
    const float* __restrict__ Ab, const double* __restrict__ pb,
    const float* __restrict__ gb, const float* __restrict__ eb,
    const unsigned* __restrict__ Wfb, const float* __restrict__ bb, float* __restrict__ outb)
{
    const int job = blockIdx.z;
    const float* A = job ? Ab : Aa;  const double* p = job ? pb : pa;
    const float* g = job ? gb : ga;  const float* e = job ? eb : ea;
    const unsigned* Wf = job ? Wfb : Wfa;
    const float* bias = job ? bb : ba;
    float* out = job ? outb : outa;

    __shared__ float stA[128], stB[128];
    __shared__ __align__(16) unsigned Al[16 * 132];   // +4 pad: 2-way banks
    const int tid = threadIdx.x;
    const int r0 = blockIdx.x * 16;

    compute_st(p, g, e, stA, stB, tid, 256);
    __syncthreads();

    for (int t = tid; t < 16 * 128; t += 256) {
        int r = t >> 7, c = t & 127;
        float v = fmaxf(fmaf(stA[c], A[(size_t)(r0 + r) * 128 + c], stB[c]), 0.0f);
        Al[r * 132 + c] = splitpack(v);
    }
    __syncthreads();

    const int lane = tid & 63, wv = tid >> 6;
    const int ct0 = blockIdx.y * 8 + wv * 2;
    const int col0 = ct0 * 16 + (lane & 15);
    const float bz0 = bias[col0], bz1 = bias[col0 + 16];
    ffrag acc0 = {bz0, bz0, bz0, bz0};
    ffrag acc1 = {bz1, bz1, bz1, bz1};

    const unsigned* ap0 = Al + (lane & 15) * 132 + (lane >> 4) * 8;

#pragma unroll
    for (int kb = 0; kb < 4; ++kb) {
        const uint4* ap = (const uint4*)(ap0 + kb * 32);
        uint4 aq0 = ap[0], aq1 = ap[1];
        bfrag ah, al; UNPK8(ah, al, aq0, aq1)
        {
            const uint4* bp = (const uint4*)(Wf + ((size_t)(ct0 * 4 + kb) * 64 + lane) * 8);
            uint4 bq0 = bp[0], bq1 = bp[1];
            bfrag bh, bl; UNPK8(bh, bl, bq0, bq1)
            acc0 = __builtin_amdgcn_mfma_f32_16x16x32_bf16(ah, bh, acc0, 0, 0, 0);
            acc0 = __builtin_amdgcn_mfma_f32_16x16x32_bf16(al, bh, acc0, 0, 0, 0);
            acc0 = __builtin_amdgcn_mfma_f32_16x16x32_bf16(ah, bl, acc0, 0, 0, 0);
        }
        {
            const uint4* bp = (const uint4*)(Wf + ((size_t)((ct0 + 1) * 4 + kb) * 64 + lane) * 8);
            uint4 bq0 = bp[0], bq1 = bp[1];
            bfrag bh, bl; UNPK8(bh, bl, bq0, bq1)
            acc1 = __builtin_amdgcn_mfma_f32_16x16x32_bf16(ah, bh, acc1, 0, 0, 0);
            acc1 = __builtin_amdgcn_mfma_f32_16x16x32_bf16(al, bh, acc1, 0, 0, 0);
            acc1 = __builtin_amdgcn_mfma_f32_16x16x32_bf16(ah, bl, acc1, 0, 0, 0);
        }
    }

    const int rowb = r0 + (lane >> 4) * 4;     // verified C/D layout [m89/m91]
#pragma unroll
    for (int j = 0; j < 4; ++j) {
        out[(size_t)(rowb + j) * 256 + col0]      = acc0[j];
        out[(size_t)(rowb + j) * 256 + col0 + 16] = acc1[j];
    }
}

// ---------------------------------------------------------------------------
// Kernel 4: conv-layer apply (unchanged round-6 body)
// ---------------------------------------------------------------------------
__global__ __launch_bounds__(128) void layer_kernel(
    const float4* __restrict__ nd, const int* __restrict__ idxbuf,
    const float* dir0, const float* fo0, float* out0, int K0,
    const float* dir1, const float* fo1, float* out1, int K1)
{
    const int job = blockIdx.y;
    const float* dirs = job ? dir1 : dir0;
    const float* fo = job ? fo1 : fo0;
    float* out = job ? out1 : out0;
    const int K = job ? K1 : K0;

    const int d = threadIdx.x;
    const int row = blockIdx.x;

    float dx = dirs[d], dy = dirs[128 + d], dz = dirs[256 + d];
    float di = 1.0f / fmaxf(sqrtf((dx * dx + dy * dy) + dz * dz), 1e-12f);
    dx *= di; dy *= di; dz *= di;

    const float4* ns = nd + (size_t)row * 100;
    const int* ib = idxbuf + (size_t)row * 100;

    float acc = -1e30f;
    for (int k4 = 0; k4 < K; k4 += 4) {
        int4 ix4 = *(const int4*)&ib[k4];
        float fs0 = fo[(size_t)ix4.x * 256 + 128 + d];
        float fs1 = fo[(size_t)ix4.y * 256 + 128 + d];
        float fs2 = fo[(size_t)ix4.z * 256 + 128 + d];
        float fs3 = fo[(size_t)ix4.w * 256 + 128 + d];
        float4 v0 = ns[k4 + 0];
        float4 v1 = ns[k4 + 1];
        float4 v2 = ns[k4 + 2];
        float4 v3 = ns[k4 + 3];
        float t0 = fmaxf((v0.x * dx + v0.y * dy) + v0.z * dz, 0.0f);
        float t1 = fmaxf((v1.x * dx + v1.y * dy) + v1.z * dz, 0.0f);
        float t2 = fmaxf((v2.x * dx + v2.y * dy) + v2.z * dz, 0.0f);
        float t3 = fmaxf((v3.x * dx + v3.y * dy) + v3.z * dz, 0.0f);
        acc = fmaxf(acc, t0 * fs0);
        acc = fmaxf(acc, t1 * fs1);
        acc = fmaxf(acc, t2 * fs2);
        acc = fmaxf(acc, t3 * fs3);
    }
    out[row * 128 + d] = fo[row * 256 + d] + acc;
}

// ---------------------------------------------------------------------------
// Kernel 5: final GEMM (CIN=384) via split-bf16 MFMA, same structure as
// gemm2 (16x128 block tile, grid (256,2)), 3 A-segments, final relu.
// ---------------------------------------------------------------------------
__global__ __launch_bounds__(256) void gemmf_kernel(
    const float* __restrict__ A0, const double* __restrict__ p0,
    const float* __restrict__ g0, const float* __restrict__ e0,
    const float* __restrict__ A1, const double* __restrict__ p1,
    const float* __restrict__ g1, const float* __restrict__ e1,
    const float* __restrict__ A2, const double* __restrict__ p2,
    const float* __restrict__ g2, const float* __restrict__ e2,
    const unsigned* __restrict__ Wf, const float* __restrict__ bias,
    float* __restrict__ out)
{
    __shared__ float stA[384], stB[384];
    __shared__ __align__(16) unsigned Al[16 * 388];   // +4 pad
    const int tid = threadIdx.x;
    const int r0 = blockIdx.x * 16;

    compute_st(p0, g0, e0, stA,       stB,       tid, 256);
    compute_st(p1, g1, e1, stA + 128, stB + 128, tid, 256);
    compute_st(p2, g2, e2, stA + 256, stB + 256, tid, 256);
    __syncthreads();

    for (int t = tid; t < 16 * 384; t += 256) {
        int r = t / 384, c = t - r * 384;
        int seg = c >> 7, cc = c & 127;
        const float* A = (seg == 0) ? A0 : (seg == 1) ? A1 : A2;
        float v = fmaxf(fmaf(stA[c], A[(size_t)(r0 + r) * 128 + cc], stB[c]), 0.0f);
        Al[r * 388 + c] = splitpack(v);
    }
    __syncthreads();

    const int lane = tid & 63, wv = tid >> 6;
    const int ct0 = blockIdx.y * 8 + wv * 2;
    const int col0 = ct0 * 16 + (lane & 15);
    const float bz0 = bias[col0], bz1 = bias[col0 + 16];
    ffrag acc0 = {bz0, bz0, bz0, bz0};
    ffrag acc1 = {bz1, bz1, bz1, bz1};

    const unsigned* ap0 = Al + (lane & 15) * 388 + (lane >> 4) * 8;

#pragma unroll
    for (int kb = 0; kb < 12; ++kb) {
        const uint4* ap = (const uint4*)(ap0 + kb * 32);
        uint4 aq0 = ap[0], aq1 = ap[1];
        bfrag ah, al; UNPK8(ah, al, aq0, aq1)
        {
            const uint4* bp = (const uint4*)(Wf + ((size_t)(ct0 * 12 + kb) * 64 + lane) * 8);
            uint4 bq0 = bp[0], bq1 = bp[1];
            bfrag bh, bl; UNPK8(bh, bl, bq0, bq1)
            acc0 = __builtin_amdgcn_mfma_f32_16x16x32_bf16(ah, bh, acc0, 0, 0, 0);
            acc0 = __builtin_amdgcn_mfma_f32_16x16x32_bf16(al, bh, acc0, 0, 0, 0);
            acc0 = __builtin_amdgcn_mfma_f32_16x16x32_bf16(ah, bl, acc0, 0, 0, 0);
        }
        {
            const uint4* bp = (const uint4*)(Wf + ((size_t)((ct0 + 1) * 12 + kb) * 64 + lane) * 8);
            uint4 bq0 = bp[0], bq1 = bp[1];
            bfrag bh, bl; UNPK8(bh, bl, bq0, bq1)
            acc1 = __builtin_amdgcn_mfma_f32_16x16x32_bf16(ah, bh, acc1, 0, 0, 0);
            acc1 = __builtin_amdgcn_mfma_f32_16x16x32_bf16(al, bh, acc1, 0, 0, 0);
            acc1 = __builtin_amdgcn_mfma_f32_16x16x32_bf16(ah, bl, acc1, 0, 0, 0);
        }
    }

    const int rowb = r0 + (lane >> 4) * 4;     // verified C/D layout [m89/m91]
#pragma unroll
    for (int j = 0; j < 4; ++j) {
        out[(size_t)(rowb + j) * 256 + col0]      = fmaxf(acc0[j], 0.0f);
        out[(size_t)(rowb + j) * 256 + col0 + 16] = fmaxf(acc1[j], 0.0f);
    }
}

// ---------------------------------------------------------------------------
extern "C" void kernel_launch(void* const* d_in, const int* in_sizes, int n_in,
                              void* d_out, int out_size, void* d_ws, size_t ws_size,
                              hipStream_t stream)
{
    (void)in_sizes; (void)n_in; (void)out_size; (void)ws_size;

    const float* verts   = (const float*)d_in[0];
    const float* dirs_l  = (const float*)d_in[1];
    const float* dirs_m0 = (const float*)d_in[2];
    const float* W_m1    = (const float*)d_in[3];
    const float* b_m1    = (const float*)d_in[4];
    const float* dirs_m1 = (const float*)d_in[5];
    const float* dirs_g0 = (const float*)d_in[6];
    const float* W_g1    = (const float*)d_in[7];
    const float* b_g1    = (const float*)d_in[8];
    const float* dirs_g1 = (const float*)d_in[9];
    const float* W_g2    = (const float*)d_in[10];
    const float* b_g2    = (const float*)d_in[11];
    const float* dirs_g2 = (const float*)d_in[12];
    const float* g_l  = (const float*)d_in[13]; const float* be_l  = (const float*)d_in[14];
    const float* g_m0 = (const float*)d_in[15]; const float* be_m0 = (const float*)d_in[16];
    const float* g_m1 = (const float*)d_in[17]; const float* be_m1 = (const float*)d_in[18];
    const float* g_g0 = (const float*)d_in[19]; const float* be_g0 = (const float*)d_in[20];
    const float* g_g1 = (const float*)d_in[21]; const float* be_g1 = (const float*)d_in[22];
    const float* g_g2 = (const float*)d_in[23]; const float* be_g2 = (const float*)d_in[24];
    const float* W_down = (const float*)d_in[25];
    const float* b_down = (const float*)d_in[26];

    char* ws = (char*)d_ws;
    const size_t MB = 1 << 20;
    int*    idx100 = (int*)   (ws + 0);               // 1.64 MB
    double* p_l    = (double*)(ws + 2 * MB);          // 6 x 128 KB fp64 partials
    double* p_m0   = p_l  + 32768;
    double* p_m1   = p_m0 + 32768;
    double* p_g0   = p_m1 + 32768;
    double* p_g1   = p_g0 + 32768;
    double* p_g2   = p_g1 + 32768;
    float4* nd100  = (float4*)(ws + 4 * MB);          // 6.55 MB (stride-4)
    float* raw_l  = (float*)(ws + 11 * MB);           // 2 MB each
    float* raw_m0 = (float*)(ws + 13 * MB);
    float* raw_g0 = (float*)(ws + 15 * MB);
    float* raw_m1 = (float*)(ws + 17 * MB);
    float* raw_g1 = (float*)(ws + 19 * MB);
    float* raw_g2 = (float*)(ws + 21 * MB);
    float* fo_m   = (float*)(ws + 23 * MB);           // 4 MB each
    float* fo_g   = (float*)(ws + 27 * MB);
    float* fo_g2  = (float*)(ws + 31 * MB);
    unsigned* wf_m1 = (unsigned*)(ws + 36 * MB);      // 128 KB each (frag W)
    unsigned* wf_g1 = (unsigned*)(ws + 37 * MB);
    unsigned* wf_g2 = (unsigned*)(ws + 38 * MB);
    unsigned* wf_dn = (unsigned*)(ws + 39 * MB);      // 384 KB

    // L1. KNN + nd + fused surface convs + W->split-bf16 fragment conversion
    knnsurf_kernel<<<1024, 256, 0, stream>>>(verts, idx100, nd100,
                                             dirs_l, dirs_m0, dirs_g0,
                                             raw_l, raw_m0, raw_g0,
                                             W_m1, W_g1, W_g2, W_down,
                                             wf_m1, wf_g1, wf_g2, wf_dn);
    // L2. BN partials for l, m0, g0
    bnsum_kernel<<<192, 256, 0, stream>>>(raw_l, p_l, raw_m0, p_m0, raw_g0, p_g0);
    // L3. fo_m = bn_relu(raw_m0) @ W_m1 ; fo_g = bn_relu(raw_g0) @ W_g1  (MFMA)
    gemm2_kernel<<<dim3(256, 2, 2), 256, 0, stream>>>(
        raw_m0, p_m0, g_m0, be_m0, wf_m1, b_m1, fo_m,
        raw_g0, p_g0, g_g0, be_g0, wf_g1, b_g1, fo_g);
    // L4. conv-layer apply (m1: K=20, g1: K=100)
    layer_kernel<<<dim3(4096, 2), 128, 0, stream>>>(nd100, idx100,
                                                    dirs_m1, fo_m, raw_m1, 20,
                                                    dirs_g1, fo_g, raw_g1, 100);
    // L5. BN partials for m1, g1
    bnsum_kernel<<<128, 256, 0, stream>>>(raw_m1, p_m1, raw_g1, p_g1, raw_g1, p_g1);
    // L6. fo_g2 = bn_relu(raw_g1) @ W_g2  (MFMA)
    gemm2_kernel<<<dim3(256, 2, 1), 256, 0, stream>>>(
        raw_g1, p_g1, g_g1, be_g1, wf_g2, b_g2, fo_g2,
        raw_g1, p_g1, g_g1, be_g1, wf_g2, b_g2, fo_g2);
    // L7. conv-layer apply (g2: K=100)
    layer_kernel<<<dim3(4096, 1), 128, 0, stream>>>(nd100, idx100,
                                                    dirs_g2, fo_g2, raw_g2, 100,
                                                    dirs_g2, fo_g2, raw_g2, 100);
    // L8. BN partials for g2
    bnsum_kernel<<<64, 256, 0, stream>>>(raw_g2, p_g2, raw_g2, p_g2, raw_g2, p_g2);
    // L9. final: relu(concat(bn_relu each) @ W_down + b_down) -> fp32 out (MFMA)
    gemmf_kernel<<<dim3(256, 2), 256, 0, stream>>>(raw_l, p_l, g_l, be_l,
                                                   raw_m1, p_m1, g_m1, be_m1,
                                                   raw_g2, p_g2, g_g2, be_g2,
                                                   wf_dn, b_down, (float*)d_out);
}